// Round 2
// baseline (971.931 us; speedup 1.0000x reference)
//
#include <hip/hip_runtime.h>

#define CCH 64
#define KOFF 27
#define EPSV 1e-5f

// ---------------------------------------------------------------- zero stats
__global__ __launch_bounds__(256) void k_zero(float* __restrict__ p) {
    p[threadIdx.x] = 0.0f;
}

// ------------------------------------------------- per-channel sum / sumsq
// block = 256 threads = 4 row-groups x 64 channels; coalesced 256B row reads
__global__ __launch_bounds__(256) void k_stats(const float* __restrict__ x, int N,
                                               float* __restrict__ sum,
                                               float* __restrict__ sumsq) {
    const int c  = threadIdx.x & 63;
    const int rg = threadIdx.x >> 6;   // 0..3
    float s = 0.0f, s2 = 0.0f;
    for (int r = blockIdx.x * 4 + rg; r < N; r += gridDim.x * 4) {
        float v = x[(size_t)r * CCH + c];
        s  += v;
        s2 += v * v;
    }
    __shared__ float sh[8][64];
    sh[rg][c]     = s;
    sh[4 + rg][c] = s2;
    __syncthreads();
    if (threadIdx.x < 64) {
        atomicAdd(&sum[c], sh[0][c] + sh[1][c] + sh[2][c] + sh[3][c]);
    } else if (threadIdx.x < 128) {
        const int cc = threadIdx.x - 64;
        atomicAdd(&sumsq[cc], sh[4][cc] + sh[5][cc] + sh[6][cc] + sh[7][cc]);
    }
}

// ------------------------------------- BN (training stats) + ReLU, f4 vec.
// Writes rows [0, N]: row N is the zero pad row used for kmap misses.
__global__ __launch_bounds__(256) void k_bnrelu(const float* __restrict__ x,
                                                const float* __restrict__ sum,
                                                const float* __restrict__ sumsq,
                                                const float* __restrict__ gamma,
                                                const float* __restrict__ beta,
                                                float* __restrict__ h, int N) {
    const float invN = 1.0f / (float)N;
    const size_t total = (size_t)(N + 1) * (CCH / 4);
    for (size_t i = (size_t)blockIdx.x * blockDim.x + threadIdx.x; i < total;
         i += (size_t)gridDim.x * blockDim.x) {
        const int r  = (int)(i >> 4);
        const int c0 = ((int)(i & 15)) * 4;
        float4 o = make_float4(0.f, 0.f, 0.f, 0.f);
        if (r < N) {
            const float4 v = ((const float4*)x)[i];
            float vv[4] = {v.x, v.y, v.z, v.w};
            float oo[4];
#pragma unroll
            for (int j = 0; j < 4; ++j) {
                const int c   = c0 + j;
                const float m = sum[c] * invN;
                const float var = sumsq[c] * invN - m * m;
                const float inv = rsqrtf(var + EPSV);
                const float sc  = gamma[c] * inv;
                const float sh_ = beta[c] - m * sc;
                const float t   = vv[j] * sc + sh_;
                oo[j] = t > 0.0f ? t : 0.0f;
            }
            o = make_float4(oo[0], oo[1], oo[2], oo[3]);
        }
        ((float4*)h)[i] = o;
    }
}

// --------------------------------------------------------- gather-GEMM conv
// Block: 64 points x 64 out-channels. 256 threads, each owns a 4x4 register
// tile: d0=(t&15)*4, p0=(t>>4)*4. Per k: gather 64 neighbor rows into
// transposed LDS sh[c][p] (stride 68 -> b128-aligned, reads broadcast,
// writes 4-way-conflict but only 16 instr per 1024 VALU), then 64 c-iters
// of {1 ds_read_b128, 1 float4 W load (L1), 16 FMA}, unrolled x4.
__global__ __launch_bounds__(256) void k_conv(const float* __restrict__ h,
                                              const int* __restrict__ kmap,
                                              const float* __restrict__ W,
                                              const float* __restrict__ resid,
                                              float* __restrict__ out, int N) {
    __shared__ float sh[CCH][68];        // [c][p], pad 64->68 floats
    __shared__ int   sidx[64 * KOFF];    // kmap slab for this block's rows

    const int base  = blockIdx.x * 64;
    const int nrows = min(64, N - base);
    const int t     = threadIdx.x;

    // contiguous coalesced kmap slab load: kmap[(base+r)*27 + k] = slab[r*27+k]
    for (int j = t; j < nrows * KOFF; j += 256) sidx[j] = kmap[(size_t)base * KOFF + j];

    const int dgrp = t & 15;          // out-channel group
    const int p0   = (t >> 4) * 4;    // point group
    const int d0   = dgrp * 4;
    const int r    = t >> 2;          // gather: row this thread serves
    const int q    = t & 3;           // gather: quarter of the 64-ch row

    float acc[4][4];
#pragma unroll
    for (int i = 0; i < 4; ++i)
#pragma unroll
        for (int j = 0; j < 4; ++j) acc[i][j] = 0.0f;

    for (int k = 0; k < KOFF; ++k) {
        __syncthreads();  // sidx ready (k=0) / sh no longer read (k>0)

        // gather one 64x64 tile, transposed into sh[c][p]
        const int idx = (r < nrows) ? sidx[r * KOFF + k] : N;  // N -> zero row
        const float4* src = (const float4*)(h + (size_t)idx * CCH + q * 16);
        const float4 v0 = src[0], v1 = src[1], v2 = src[2], v3 = src[3];
        const float vals[16] = {v0.x, v0.y, v0.z, v0.w, v1.x, v1.y, v1.z, v1.w,
                                v2.x, v2.y, v2.z, v2.w, v3.x, v3.y, v3.z, v3.w};
#pragma unroll
        for (int j = 0; j < 16; ++j) sh[q * 16 + j][r] = vals[j];
        __syncthreads();

        const float4* wk = (const float4*)(W + (size_t)k * CCH * CCH) + dgrp;
#pragma unroll 4
        for (int c = 0; c < CCH; ++c) {
            const float4 w  = wk[c * 16];                           // W[k][c][d0..d0+3]
            const float4 hv = *(const float4*)&sh[c][p0];           // h[p0..p0+3][c]
            acc[0][0] += hv.x * w.x; acc[0][1] += hv.x * w.y; acc[0][2] += hv.x * w.z; acc[0][3] += hv.x * w.w;
            acc[1][0] += hv.y * w.x; acc[1][1] += hv.y * w.y; acc[1][2] += hv.y * w.z; acc[1][3] += hv.y * w.w;
            acc[2][0] += hv.z * w.x; acc[2][1] += hv.z * w.y; acc[2][2] += hv.z * w.z; acc[2][3] += hv.z * w.w;
            acc[3][0] += hv.w * w.x; acc[3][1] += hv.w * w.y; acc[3][2] += hv.w * w.z; acc[3][3] += hv.w * w.w;
        }
    }

#pragma unroll
    for (int pi = 0; pi < 4; ++pi) {
        const int row = base + p0 + pi;
        if (row < N) {
            float4 o = make_float4(acc[pi][0], acc[pi][1], acc[pi][2], acc[pi][3]);
            if (resid) {
                const float4 rr = *(const float4*)(resid + (size_t)row * CCH + d0);
                o.x += rr.x; o.y += rr.y; o.z += rr.z; o.w += rr.w;
            }
            *(float4*)(out + (size_t)row * CCH + d0) = o;
        }
    }
}

// ---------------------------------------------------------------- launcher
extern "C" void kernel_launch(void* const* d_in, const int* in_sizes, int n_in,
                              void* d_out, int out_size, void* d_ws, size_t ws_size,
                              hipStream_t stream) {
    const float* x      = (const float*)d_in[0];
    const int*   kmap   = (const int*)d_in[1];
    const float* gamma1 = (const float*)d_in[2];
    const float* beta1  = (const float*)d_in[3];
    const float* W1     = (const float*)d_in[4];
    const float* gamma2 = (const float*)d_in[5];
    const float* beta2  = (const float*)d_in[6];
    const float* W2     = (const float*)d_in[7];
    float*       out    = (float*)d_out;

    const int N = in_sizes[0] / CCH;  // 100000

    float* h     = (float*)d_ws;                       // (N+1) x 64
    float* stats = h + (size_t)(N + 1) * CCH;          // 256 floats

    k_zero<<<1, 256, 0, stream>>>(stats);

    const int sgrid = 1024;
    const int cgrid = (N + 63) / 64;

    // --- block 1: BN1 -> ReLU -> conv(W1) -> out (used as intermediate)
    k_stats <<<sgrid, 256, 0, stream>>>(x, N, stats + 0, stats + 64);
    k_bnrelu<<<2048, 256, 0, stream>>>(x, stats + 0, stats + 64, gamma1, beta1, h, N);
    k_conv  <<<cgrid, 256, 0, stream>>>(h, kmap, W1, nullptr, out, N);

    // --- block 2: BN2 -> ReLU -> conv(W2) + residual(x) -> out
    k_stats <<<sgrid, 256, 0, stream>>>(out, N, stats + 128, stats + 192);
    k_bnrelu<<<2048, 256, 0, stream>>>(out, stats + 128, stats + 192, gamma2, beta2, h, N);
    k_conv  <<<cgrid, 256, 0, stream>>>(h, kmap, W2, x, out, N);
}

// Round 3
// 553.924 us; speedup vs baseline: 1.7546x; 1.7546x over previous
//
#include <hip/hip_runtime.h>
#include <hip/hip_bf16.h>

#define CCH 64
#define KOFF 27
#define EPSV 1e-5f

typedef short   bf16x8 __attribute__((ext_vector_type(8)));
typedef float   f32x4  __attribute__((ext_vector_type(4)));

// ---------------------------------------------------------------- zero stats
__global__ __launch_bounds__(256) void k_zero(float* __restrict__ p) {
    p[threadIdx.x] = 0.0f;
}

// ------------------------------------------------- per-channel sum / sumsq
__global__ __launch_bounds__(256) void k_stats(const float* __restrict__ x, int N,
                                               float* __restrict__ sum,
                                               float* __restrict__ sumsq) {
    const int c  = threadIdx.x & 63;
    const int rg = threadIdx.x >> 6;   // 0..3
    float s = 0.0f, s2 = 0.0f;
    for (int r = blockIdx.x * 4 + rg; r < N; r += gridDim.x * 4) {
        float v = x[(size_t)r * CCH + c];
        s  += v;
        s2 += v * v;
    }
    __shared__ float sh[8][64];
    sh[rg][c]     = s;
    sh[4 + rg][c] = s2;
    __syncthreads();
    if (threadIdx.x < 64) {
        atomicAdd(&sum[c], sh[0][c] + sh[1][c] + sh[2][c] + sh[3][c]);
    } else if (threadIdx.x < 128) {
        const int cc = threadIdx.x - 64;
        atomicAdd(&sumsq[cc], sh[4][cc] + sh[5][cc] + sh[6][cc] + sh[7][cc]);
    }
}

// ---------------- BN (training stats) + ReLU -> bf16 rows, zero pad row N
__global__ __launch_bounds__(256) void k_bnrelu_bf16(const float* __restrict__ x,
                                                     const float* __restrict__ sum,
                                                     const float* __restrict__ sumsq,
                                                     const float* __restrict__ gamma,
                                                     const float* __restrict__ beta,
                                                     __hip_bfloat16* __restrict__ h,
                                                     int N) {
    const float invN = 1.0f / (float)N;
    const int total = (N + 1) * 8;            // groups of 8 channels (16B bf16)
    for (int i = blockIdx.x * 256 + threadIdx.x; i < total; i += gridDim.x * 256) {
        const int r  = i >> 3;
        const int c0 = (i & 7) * 8;
        union { __hip_bfloat16 b[8]; int4 v; } pk;
        if (r < N) {
            const float4 va = ((const float4*)x)[i * 2];
            const float4 vb = ((const float4*)x)[i * 2 + 1];
            const float vv[8] = {va.x, va.y, va.z, va.w, vb.x, vb.y, vb.z, vb.w};
#pragma unroll
            for (int j = 0; j < 8; ++j) {
                const int c     = c0 + j;
                const float m   = sum[c] * invN;
                const float var = sumsq[c] * invN - m * m;
                const float sc  = gamma[c] * rsqrtf(var + EPSV);
                const float sh_ = beta[c] - m * sc;
                float t = vv[j] * sc + sh_;
                t = t > 0.0f ? t : 0.0f;
                pk.b[j] = __float2bfloat16(t);
            }
        } else {
            pk.v = make_int4(0, 0, 0, 0);     // zero pad row for kmap misses
        }
        ((int4*)h)[i] = pk.v;
    }
}

// --------------- W[k][c][d] fp32 -> Wt[k][d][c] bf16 (tiny, L2-resident)
__global__ __launch_bounds__(256) void k_wt(const float* __restrict__ W,
                                            __hip_bfloat16* __restrict__ Wt) {
    const int k = blockIdx.x;
    const float* src = W + (size_t)k * CCH * CCH;
    __hip_bfloat16* dst = Wt + (size_t)k * CCH * CCH;
    for (int i = threadIdx.x; i < CCH * CCH; i += 256) {
        const int d = i >> 6, c = i & 63;
        dst[i] = __float2bfloat16(src[c * CCH + d]);   // dst[d][c] = src[c][d]
    }
}

// ------------------------------------------ MFMA gather-conv, zero LDS.
// Block = 4 waves; wave w computes points [base+16w, base+16w+16) x 64 chans.
// Per k-offset: A-frag gathered straight from h_bf16 rows (16B/lane),
// B-frag from transposed Wt (16B/lane, L1-hot), 8 x mfma_f32_16x16x32_bf16.
__global__ __launch_bounds__(256) void k_conv_mfma(const __hip_bfloat16* __restrict__ h,
                                                   const int* __restrict__ kmap,
                                                   const __hip_bfloat16* __restrict__ Wt,
                                                   const float* __restrict__ resid,
                                                   float* __restrict__ out, int N) {
    const int lane  = threadIdx.x & 63;
    const int wave  = threadIdx.x >> 6;
    const int p0    = blockIdx.x * 64 + wave * 16;   // wave's first point
    const int col16 = lane & 15;
    const int chunk = lane >> 4;                     // 0..3
    const int prow  = p0 + col16;                    // row this lane gathers
    const bool valid = prow < N;

    const int* kp = kmap + (size_t)(valid ? prow : 0) * KOFF;
    const bf16x8* wbase = (const bf16x8*)(Wt) + (size_t)col16 * 8 + chunk; // (col16*64+chunk*8)/8

    f32x4 acc[4] = {};

    for (int k = 0; k < KOFF; ++k) {
        const int idx = valid ? kp[k] : N;           // N -> zero pad row
        const bf16x8* arow = (const bf16x8*)(h + (size_t)idx * CCH) + chunk;
        const bf16x8 a0 = arow[0];                   // c = chunk*8 .. +8
        const bf16x8 a1 = arow[4];                   // c = 32+chunk*8 .. +8
        const bf16x8* wb = wbase + (size_t)k * (CCH * CCH / 8);
#pragma unroll
        for (int n = 0; n < 4; ++n) {
            const bf16x8 b0 = wb[n * 128];           // d = n*16+col16, c = chunk*8..
            const bf16x8 b1 = wb[n * 128 + 4];       // ... c += 32
            acc[n] = __builtin_amdgcn_mfma_f32_16x16x32_bf16(a0, b0, acc[n], 0, 0, 0);
            acc[n] = __builtin_amdgcn_mfma_f32_16x16x32_bf16(a1, b1, acc[n], 0, 0, 0);
        }
    }

    // D layout: col = lane&15, row = (lane>>4)*4 + reg   [m89-verified]
#pragma unroll
    for (int n = 0; n < 4; ++n) {
        const int col = n * 16 + col16;
#pragma unroll
        for (int j = 0; j < 4; ++j) {
            const int row = p0 + chunk * 4 + j;
            if (row < N) {
                float v = acc[n][j];
                if (resid) v += resid[(size_t)row * CCH + col];
                out[(size_t)row * CCH + col] = v;
            }
        }
    }
}

// ---------------------------------------------------------------- launcher
extern "C" void kernel_launch(void* const* d_in, const int* in_sizes, int n_in,
                              void* d_out, int out_size, void* d_ws, size_t ws_size,
                              hipStream_t stream) {
    const float* x      = (const float*)d_in[0];
    const int*   kmap   = (const int*)d_in[1];
    const float* gamma1 = (const float*)d_in[2];
    const float* beta1  = (const float*)d_in[3];
    const float* W1     = (const float*)d_in[4];
    const float* gamma2 = (const float*)d_in[5];
    const float* beta2  = (const float*)d_in[6];
    const float* W2     = (const float*)d_in[7];
    float*       out    = (float*)d_out;

    const int N = in_sizes[0] / CCH;  // 100000

    // ws layout (all 256B-aligned): h_bf16 [(N+1)][64] | Wt1 | Wt2 | stats
    char* wp = (char*)d_ws;
    __hip_bfloat16* hbuf = (__hip_bfloat16*)wp;            wp += ((size_t)(N + 1) * CCH * 2 + 255) & ~255ull;
    __hip_bfloat16* Wt1  = (__hip_bfloat16*)wp;            wp += (KOFF * CCH * CCH * 2 + 255) & ~255ull;
    __hip_bfloat16* Wt2  = (__hip_bfloat16*)wp;            wp += (KOFF * CCH * CCH * 2 + 255) & ~255ull;
    float*          stats = (float*)wp;

    const int cgrid = (N + 63) / 64;

    k_zero<<<1, 256, 0, stream>>>(stats);
    k_wt  <<<KOFF, 256, 0, stream>>>(W1, Wt1);
    k_wt  <<<KOFF, 256, 0, stream>>>(W2, Wt2);

    // --- block 1: BN1 -> ReLU -> conv(W1) -> d_out (fp32 intermediate)
    k_stats      <<<1024, 256, 0, stream>>>(x, N, stats + 0, stats + 64);
    k_bnrelu_bf16<<<2048, 256, 0, stream>>>(x, stats + 0, stats + 64, gamma1, beta1, hbuf, N);
    k_conv_mfma  <<<cgrid, 256, 0, stream>>>(hbuf, kmap, Wt1, nullptr, out, N);

    // --- block 2: BN2 -> ReLU -> conv(W2) + residual(x) -> d_out
    k_stats      <<<1024, 256, 0, stream>>>(out, N, stats + 128, stats + 192);
    k_bnrelu_bf16<<<2048, 256, 0, stream>>>(out, stats + 128, stats + 192, gamma2, beta2, hbuf, N);
    k_conv_mfma  <<<cgrid, 256, 0, stream>>>(hbuf, kmap, Wt2, x, out, N);
}

// Round 7
// 241.311 us; speedup vs baseline: 4.0277x; 2.2955x over previous
//
#include <hip/hip_runtime.h>
#include <hip/hip_bf16.h>

#define CCH 64
#define KOFF 27
#define EPSV 1e-5f

typedef short bf16x8 __attribute__((ext_vector_type(8)));
typedef float f32x4  __attribute__((ext_vector_type(4)));

__device__ __forceinline__ void gld16(const void* g, void* l) {
    __builtin_amdgcn_global_load_lds((const __attribute__((address_space(1))) void*)g,
                                     (__attribute__((address_space(3))) void*)l, 16, 0, 0);
}

// ------------------------------------------------- per-channel sum / sumsq
__global__ __launch_bounds__(256) void k_stats(const float* __restrict__ x, int N,
                                               float* __restrict__ sum,
                                               float* __restrict__ sumsq) {
    const int c  = threadIdx.x & 63;
    const int rg = threadIdx.x >> 6;   // 0..3
    float s = 0.0f, s2 = 0.0f;
    for (int r = blockIdx.x * 4 + rg; r < N; r += gridDim.x * 4) {
        float v = x[(size_t)r * CCH + c];
        s  += v;
        s2 += v * v;
    }
    __shared__ float sh[8][64];
    sh[rg][c]     = s;
    sh[4 + rg][c] = s2;
    __syncthreads();
    if (threadIdx.x < 64) {
        atomicAdd(&sum[c], sh[0][c] + sh[1][c] + sh[2][c] + sh[3][c]);
    } else if (threadIdx.x < 128) {
        const int cc = threadIdx.x - 64;
        atomicAdd(&sumsq[cc], sh[4][cc] + sh[5][cc] + sh[6][cc] + sh[7][cc]);
    }
}

// ---------------- BN (training stats) + ReLU -> bf16 rows, zero pad row N
__global__ __launch_bounds__(256) void k_bnrelu_bf16(const float* __restrict__ x,
                                                     const float* __restrict__ sum,
                                                     const float* __restrict__ sumsq,
                                                     const float* __restrict__ gamma,
                                                     const float* __restrict__ beta,
                                                     __hip_bfloat16* __restrict__ h,
                                                     int N) {
    const float invN = 1.0f / (float)N;
    const int total = (N + 1) * 8;            // groups of 8 channels (16B bf16)
    for (int i = blockIdx.x * 256 + threadIdx.x; i < total; i += gridDim.x * 256) {
        const int r  = i >> 3;
        const int c0 = (i & 7) * 8;
        union { __hip_bfloat16 b[8]; int4 v; } pk;
        if (r < N) {
            const float4 va = ((const float4*)x)[i * 2];
            const float4 vb = ((const float4*)x)[i * 2 + 1];
            const float vv[8] = {va.x, va.y, va.z, va.w, vb.x, vb.y, vb.z, vb.w};
#pragma unroll
            for (int j = 0; j < 8; ++j) {
                const int c     = c0 + j;
                const float m   = sum[c] * invN;
                const float var = sumsq[c] * invN - m * m;
                const float sc  = gamma[c] * rsqrtf(var + EPSV);
                const float sh_ = beta[c] - m * sc;
                float t = vv[j] * sc + sh_;
                t = t > 0.0f ? t : 0.0f;
                pk.b[j] = __float2bfloat16(t);
            }
        } else {
            pk.v = make_int4(0, 0, 0, 0);     // zero pad row for kmap misses
        }
        ((int4*)h)[i] = pk.v;
    }
}

// --- W[k][c][d] fp32 -> fragment-order bf16 image, per k-slice 4096 elems:
// elem e: p=e>>3, j=e&7; p = ((n*2+half)*4 + chunk)*16 + col16
// value = W[k][c = chunk*8 + half*32 + j][d = n*16 + col16]
// conv reads slice as ds_read_b128 at byte (n*2+half)*1024 + lane*16 (linear!)
__global__ __launch_bounds__(256) void k_wimg(const float* __restrict__ W1,
                                              const float* __restrict__ W2,
                                              __hip_bfloat16* __restrict__ img1,
                                              __hip_bfloat16* __restrict__ img2) {
    int k = blockIdx.x;
    const float* W = W1; __hip_bfloat16* img = img1;
    if (k >= KOFF) { k -= KOFF; W = W2; img = img2; }
    const float* src = W + (size_t)k * CCH * CCH;
    __hip_bfloat16* dst = img + (size_t)k * CCH * CCH;
    for (int e = threadIdx.x; e < CCH * CCH; e += 256) {
        const int p = e >> 3, j = e & 7;
        const int n = p >> 7, half = (p >> 6) & 1, chunk = (p >> 4) & 3, col = p & 15;
        const int c = chunk * 8 + half * 32 + j;
        const int d = n * 16 + col;
        dst[e] = __float2bfloat16(src[c * CCH + d]);
    }
}

// ------------------------------------------ MFMA gather-conv.
// 4 waves x 32 points = 128 points/block, 64 out-channels.
// Per k: W-slice double-buffered in LDS via global_load_lds (linear b128
// reads, 0 conflicts); kmap slab in LDS; A gathered from global, prefetched
// one iteration ahead.
__global__ __launch_bounds__(256) void k_conv_mfma(const __hip_bfloat16* __restrict__ h,
                                                   const int* __restrict__ kmap,
                                                   const __hip_bfloat16* __restrict__ Wimg,
                                                   const float* __restrict__ resid,
                                                   float* __restrict__ out, int N) {
    __shared__ int sidx[128 * KOFF];              // 13824 B
    __shared__ __hip_bfloat16 wbuf[2][4096];      // 2 x 8 KB

    const int t     = threadIdx.x;
    const int lane  = t & 63;
    const int wave  = t >> 6;
    const int col16 = lane & 15;
    const int chunk = lane >> 4;
    const int base  = blockIdx.x * 128;
    const int p0    = base + wave * 32;

    // kmap slab, coalesced; rows >= N fall outside glim -> idx = N (zero row)
    const long gbase = (long)base * KOFF;
    const long glim  = (long)N * KOFF;
    for (int j = t; j < 128 * KOFF; j += 256)
        sidx[j] = (gbase + j < glim) ? kmap[gbase + j] : N;

    // stage W-slice k=0 (each thread copies 2 x 16B, linear)
    {
        const __hip_bfloat16* g = Wimg + t * 8;
        gld16(g,        &wbuf[0][t * 8]);
        gld16(g + 2048, &wbuf[0][t * 8 + 2048]);
    }
    __syncthreads();   // slab + buf0 ready

    const int r0 = wave * 32 + col16;   // local row, m=0
    const int r1 = r0 + 16;             // m=1

    f32x4  acc[2][4] = {};
    bf16x8 an[2][2];

    // prefetch A(k=0)
    {
        const int i0 = sidx[r0 * KOFF];
        const int i1 = sidx[r1 * KOFF];
        const bf16x8* A0 = (const bf16x8*)(h + (size_t)i0 * CCH) + chunk;
        const bf16x8* A1 = (const bf16x8*)(h + (size_t)i1 * CCH) + chunk;
        an[0][0] = A0[0]; an[0][1] = A0[4];
        an[1][0] = A1[0]; an[1][1] = A1[4];
    }

    for (int k = 0; k < KOFF; ++k) {
        // stage next W-slice into the buffer read two iters ago (protected by
        // the end-of-previous-iter barrier)
        if (k + 1 < KOFF) {
            const __hip_bfloat16* g = Wimg + (size_t)(k + 1) * 4096 + t * 8;
            const int nb = (k + 1) & 1;
            gld16(g,        &wbuf[nb][t * 8]);
            gld16(g + 2048, &wbuf[nb][t * 8 + 2048]);
        }
        // rotate prefetched A into cur, issue A(k+1)
        const bf16x8 a00 = an[0][0], a01 = an[0][1], a10 = an[1][0], a11 = an[1][1];
        if (k + 1 < KOFF) {
            const int i0 = sidx[r0 * KOFF + k + 1];
            const int i1 = sidx[r1 * KOFF + k + 1];
            const bf16x8* A0 = (const bf16x8*)(h + (size_t)i0 * CCH) + chunk;
            const bf16x8* A1 = (const bf16x8*)(h + (size_t)i1 * CCH) + chunk;
            an[0][0] = A0[0]; an[0][1] = A0[4];
            an[1][0] = A1[0]; an[1][1] = A1[4];
        }
        // B from LDS (linear b128, conflict-free) + 16 MFMAs
        const bf16x8* bp = (const bf16x8*)&wbuf[k & 1][0] + lane;
#pragma unroll
        for (int n = 0; n < 4; ++n) {
            const bf16x8 b0 = bp[(n * 2 + 0) * 64];
            const bf16x8 b1 = bp[(n * 2 + 1) * 64];
            acc[0][n] = __builtin_amdgcn_mfma_f32_16x16x32_bf16(a00, b0, acc[0][n], 0, 0, 0);
            acc[0][n] = __builtin_amdgcn_mfma_f32_16x16x32_bf16(a01, b1, acc[0][n], 0, 0, 0);
            acc[1][n] = __builtin_amdgcn_mfma_f32_16x16x32_bf16(a10, b0, acc[1][n], 0, 0, 0);
            acc[1][n] = __builtin_amdgcn_mfma_f32_16x16x32_bf16(a11, b1, acc[1][n], 0, 0, 0);
        }
        __syncthreads();  // all waves done reading wbuf[k&1]; drains prefetches
    }

    // epilogue: D col = lane&15 (out-ch), row = chunk*4 + reg  [validated r3]
#pragma unroll
    for (int m = 0; m < 2; ++m) {
#pragma unroll
        for (int n = 0; n < 4; ++n) {
            const int col = n * 16 + col16;
#pragma unroll
            for (int j = 0; j < 4; ++j) {
                const int row = p0 + m * 16 + chunk * 4 + j;
                if (row < N) {
                    float v = acc[m][n][j];
                    if (resid) v += resid[(size_t)row * CCH + col];
                    out[(size_t)row * CCH + col] = v;
                }
            }
        }
    }
}

// ---------------------------------------------------------------- launcher
extern "C" void kernel_launch(void* const* d_in, const int* in_sizes, int n_in,
                              void* d_out, int out_size, void* d_ws, size_t ws_size,
                              hipStream_t stream) {
    const float* x      = (const float*)d_in[0];
    const int*   kmap   = (const int*)d_in[1];
    const float* gamma1 = (const float*)d_in[2];
    const float* beta1  = (const float*)d_in[3];
    const float* W1     = (const float*)d_in[4];
    const float* gamma2 = (const float*)d_in[5];
    const float* beta2  = (const float*)d_in[6];
    const float* W2     = (const float*)d_in[7];
    float*       out    = (float*)d_out;

    const int N = in_sizes[0] / CCH;  // 100000

    // ws layout: h_bf16 [(N+1)][64] | img1 | img2 | stats(256 f32)
    char* wp = (char*)d_ws;
    __hip_bfloat16* hbuf = (__hip_bfloat16*)wp;  wp += ((size_t)(N + 1) * CCH * 2 + 255) & ~255ull;
    __hip_bfloat16* img1 = (__hip_bfloat16*)wp;  wp += ((size_t)KOFF * CCH * CCH * 2 + 255) & ~255ull;
    __hip_bfloat16* img2 = (__hip_bfloat16*)wp;  wp += ((size_t)KOFF * CCH * CCH * 2 + 255) & ~255ull;
    float*          stats = (float*)wp;

    hipMemsetAsync(stats, 0, 256 * sizeof(float), stream);
    k_wimg<<<2 * KOFF, 256, 0, stream>>>(W1, W2, img1, img2);

    const int cgrid = (N + 127) / 128;

    // --- block 1: BN1 -> ReLU -> conv(W1) -> d_out (fp32 intermediate)
    k_stats      <<<304,  256, 0, stream>>>(x, N, stats + 0, stats + 64);
    k_bnrelu_bf16<<<2048, 256, 0, stream>>>(x, stats + 0, stats + 64, gamma1, beta1, hbuf, N);
    k_conv_mfma  <<<cgrid, 256, 0, stream>>>(hbuf, kmap, img1, nullptr, out, N);

    // --- block 2: BN2 -> ReLU -> conv(W2) + residual(x) -> d_out
    k_stats      <<<304,  256, 0, stream>>>(out, N, stats + 128, stats + 192);
    k_bnrelu_bf16<<<2048, 256, 0, stream>>>(out, stats + 128, stats + 192, gamma2, beta2, hbuf, N);
    k_conv_mfma  <<<cgrid, 256, 0, stream>>>(hbuf, kmap, img2, x, out, N);
}